// Round 9
// baseline (313.635 us; speedup 1.0000x reference)
//
#include <hip/hip_runtime.h>
#include <math.h>

#define NB    16
#define NAg   3
#define NCg   85
#define NCLS  80
#define NGg   76
#define NSp   (NGg*NGg)     // 5776
#define NBOX  50
#define INCH  256
#define SPB   1024          // spatial positions per GEMM block (256 thr x float4)
#define GBLK  ((NSp + SPB - 1) / SPB)   // 6 GEMM blocks per batch
#define TOTALL (GBLK * NB + NB * NBOX)  // 96 + 800 = 896 ticket blocks

// ws layout (bytes)
#define ACC_OFF  0                       // 8 floats  (loss accumulators)
#define HAS_OFF  32                      // 16 ints   (per-batch has_boxes flag)
#define DONE_OFF 96                      // 1 int     (last-block ticket)
#define WT_OFF   128                     // 256*16 floats = 16384 B (transposed W)
#define GB_OFF   (WT_OFF + 16384)        // NB*NBOX*8 floats = 25600 B (IoU boxes)
#define GA_OFF   (GB_OFF + 25600)        // NB*NBOX*8 floats = 25600 B (target aux)
#define GI_OFF   (GA_OFF + 25600)        // NB*NBOX*2 ints   =  6400 B (cell, cls)

__device__ __constant__ float c_AW[9] = {1.25f,2.0f,4.125f,3.75f,7.75f,7.375f,14.5f,19.5f,46.625f};
__device__ __constant__ float c_AH[9] = {1.625f,3.75f,2.875f,7.625f,5.625f,14.875f,11.25f,24.75f,40.75f};

__device__ __forceinline__ float safe_log(float p) {
    return fmaxf(logf(fmaxf(p, 1e-12f)), -100.0f);
}
__device__ __forceinline__ float sigm(float x) {
    return 1.0f / (1.0f + expf(-x));
}

// ---- Kernel 1: label processing + W transpose + acc/done init -------------
__global__ __launch_bounds__(256) void k_labels(
    const float* __restrict__ labels, const float* __restrict__ W,
    float* __restrict__ Wt, float* __restrict__ gbox, float* __restrict__ gaux,
    int* __restrict__ gint, int* __restrict__ hasAny, float* __restrict__ acc,
    int* __restrict__ done)
{
    const int b = blockIdx.x, tid = threadIdx.x;
    const int t = b * 256 + tid;

    // transposed weights: Wt[c*16 + f] = W[row(f)*INCH + c], f<15 (slot 15 pad)
    {
        const int c = t >> 4, f = t & 15;
        Wt[t] = (f < 15) ? W[((f / 5) * NCg + (f % 5)) * INCH + c] : 0.f;
    }
    if (b == 0 && tid < 8)  acc[tid] = 0.f;
    if (b == 0 && tid == 8) *done = 0;

    int valid = 0;
    if (tid < NBOX) {
        const int bt = b * NBOX + tid;
        const float* L = labels + (size_t)bt * 5;
        const float l0 = L[0], l1 = L[1], l2 = L[2], l3 = L[3], l4 = L[4];
        valid = (l0 + l1 + l2 + l3 + l4) > 0.f;

        const float gx = l1 * NGg, gy = l2 * NGg, gw = l3 * NGg, gh = l4 * NGg;

        int best = 0; float brr = -1.f;
#pragma unroll
        for (int k = 0; k < 9; k++) {
            float inter = fminf(gw, c_AW[k]) * fminf(gh, c_AH[k]);
            float uni   = gw*gh + c_AW[k]*c_AH[k] - inter;
            float r     = inter / uni;
            if (r > brr) { brr = r; best = k; }   // first max wins (argmax)
        }
        const int a = (best <= 2) ? best : -1;
        const int assign = valid && (a >= 0);
        const int a_safe = a < 0 ? 0 : (a > 2 ? 2 : a);

        const int gi = (int)floorf(gx), gj = (int)floorf(gy);
        const int inb = (gi >= 0) && (gi < NGg) && (gj >= 0) && (gj < NGg);
        const int cell = (assign && inb) ? (a * NSp + gj * NGg + gi) : -1;

        float* gb = gbox + (size_t)bt * 8;
        gb[0] = gx - gw * 0.5f;             // x0
        gb[1] = gy - gh * 0.5f;             // y0
        gb[2] = gx + gw * 0.5f;             // x1
        gb[3] = gy + gh * 0.5f;             // y1
        gb[4] = valid ? gw * gh : -1.f;     // area, <0 => skip in IoU
        gb[5] = __int_as_float(cell);       // assigned cell (-1 none)

        float* ga = gaux + (size_t)bt * 8;
        ga[0] = gx - floorf(gx);
        ga[1] = gy - floorf(gy);
        ga[2] = logf(gw / c_AW[a_safe] + 1e-16f);
        ga[3] = logf(gh / c_AH[a_safe] + 1e-16f);
        ga[4] = 2.f - gw * gh / (float)NSp;

        gint[bt*2 + 0] = cell;
        gint[bt*2 + 1] = (int)l0;
    }
    if (tid < 64) {
        const unsigned long long m = __ballot(valid != 0);
        if (tid == 0) hasAny[b] = (m != 0ULL) ? 1 : 0;
    }
}

// ---- Kernel 2: per-assigned-box xy/wh/cls losses (independent of k_main) --
__global__ __launch_bounds__(256) void k_assigned(
    const float* __restrict__ xin, const float* __restrict__ W,
    const float* __restrict__ bias, const float* __restrict__ gaux,
    const int* __restrict__ gint, float* __restrict__ acc,
    int* __restrict__ done, float* __restrict__ out)
{
    const int t = blockIdx.x;            // box id 0..799
    const int b = t / NBOX, n = t % NBOX;
    const int tid = threadIdx.x;

    __shared__ int   scell[NBOX];
    __shared__ float4 col4[64];
    __shared__ float  xsh[NCg];
    __shared__ float  sacc[3];

    if (tid < NBOX) scell[tid] = gint[(b * NBOX + tid) * 2];
    __syncthreads();

    const int cell = scell[n];
    bool win = (cell >= 0);              // block-uniform
    if (win)
        for (int n2 = n + 1; n2 < NBOX; ++n2)
            if (scell[n2] == cell) { win = false; break; }

    if (win) {
        const int a = cell / NSp, s = cell % NSp;
        const int o0 = a * NCg;

        ((float*)col4)[tid] = xin[((size_t)b * INCH + tid) * NSp + s];
        if (tid < 3) sacc[tid] = 0.f;
        __syncthreads();

        const int wid = tid >> 6, lane = tid & 63;
        for (int o = wid; o < NCg; o += 4) {
            const float4 wv = *(const float4*)&W[(size_t)(o0 + o) * INCH + lane * 4];
            const float4 cv = col4[lane];
            float p = wv.x*cv.x + wv.y*cv.y + wv.z*cv.z + wv.w*cv.w;
            for (int off = 32; off; off >>= 1) p += __shfl_down(p, off);
            if (lane == 0) xsh[o] = p + bias[o0 + o];
        }
        __syncthreads();

        if (tid < NCg) {
            const float* ga = gaux + (size_t)t * 8;
            const float sval = ga[4];
            const int gcls = gint[t*2 + 1];
            float val = xsh[tid];
            float term; int slot;
            if (tid < 2) {                       // xy BCE * sval
                float tgt = ga[tid];
                float p = sigm(val);
                term = -(tgt * safe_log(p) + (1.f - tgt) * safe_log(1.f - p)) * sval;
                slot = 0;
            } else if (tid < 4) {                // wh MSE * 0.5*sval
                float tgt = ga[tid];             // ga[2], ga[3]
                float d = val - tgt;
                term = 0.5f * sval * d * d;
                slot = 1;
            } else if (tid == 4) {               // conf handled in k_main
                term = 0.f; slot = 2;
            } else {                             // cls BCE
                float tgt = ((tid - 5) == gcls) ? 1.f : 0.f;
                float p = sigm(val);
                term = -(tgt * safe_log(p) + (1.f - tgt) * safe_log(1.f - p));
                slot = 2;
            }
            atomicAdd(&sacc[slot], term);
        }
        __syncthreads();
        if (tid == 0) {
            atomicAdd(&acc[0], sacc[0]);
            atomicAdd(&acc[1], sacc[1]);
            atomicAdd(&acc[3], sacc[2]);
        }
    }

    // ---- finalize ticket (all blocks, win or not) -------------------------
    if (tid == 0) {
        __threadfence();
        const int v = atomicAdd(done, 1);
        if (v == TOTALL - 1) {
            const float xy = atomicAdd(&acc[0], 0.f);
            const float wh = atomicAdd(&acc[1], 0.f);
            const float ob = atomicAdd(&acc[2], 0.f);
            const float cl = atomicAdd(&acc[3], 0.f);
            out[0] = xy + wh + ob + cl;
            out[1] = xy; out[2] = wh; out[3] = ob; out[4] = cl;
        }
    }
}

// ---- Kernel 3: fused 15-ch GEMM + decode + IoU + obj BCE ------------------
// grid (6,16), 256 threads. Thread t owns 4 contiguous positions pb+4t..+3
// and the FULL 15-output accumulator in registers (no LDS partials, no
// cross-wave reduce). Per channel step, the block's 4 waves read one
// CONTIGUOUS 4KB slice of a single channel plane.
__global__ __launch_bounds__(256) void k_main(
    const float* __restrict__ xin, const float* __restrict__ Wt,
    const float* __restrict__ bias, const float* __restrict__ gbox,
    const int* __restrict__ hasAny, float* __restrict__ acc,
    int* __restrict__ done, float* __restrict__ out)
{
    __shared__ float wred[4];

    const int bx  = blockIdx.x;
    const int b   = blockIdx.y;
    const int tid = threadIdx.x;
    const int w   = tid >> 6, l = tid & 63;
    const int pb  = bx * SPB;
    const bool live = (pb + 4*tid) < NSp;    // NSp-pb divisible by 4: full float4

    // ================= phase 1: register-resident GEMM =====================
    float4 ac[15];
#pragma unroll
    for (int f = 0; f < 15; ++f) ac[f] = make_float4(0.f,0.f,0.f,0.f);

    const float* xp = xin + (size_t)b * INCH * NSp + pb + 4*tid;
    const float4 z = make_float4(0.f,0.f,0.f,0.f);

    for (int c0 = 0; c0 < INCH; c0 += 8) {
        float4 v[8];
#pragma unroll
        for (int k = 0; k < 8; ++k)
            v[k] = live ? *(const float4*)(xp + (size_t)(c0 + k) * NSp) : z;
#pragma unroll
        for (int k = 0; k < 8; ++k) {
            const float* wr = Wt + ((c0 + k) << 4);   // block-uniform -> s_load
#pragma unroll
            for (int f = 0; f < 15; ++f) {
                const float wv = wr[f];
                ac[f].x += wv * v[k].x;  ac[f].y += wv * v[k].y;
                ac[f].z += wv * v[k].z;  ac[f].w += wv * v[k].w;
            }
        }
    }

    // ================= phase 2: decode + IoU + obj BCE (registers) =========
    float lsum = 0.f;
    if (live) {
        const bool hasB = hasAny[b] != 0;
        const float* gb = gbox + (size_t)b * NBOX * 8;
#pragma unroll
        for (int q = 0; q < 4; ++q) {
            const int p = pb + 4*tid + q;
            float xv[15];
#pragma unroll
            for (int f = 0; f < 15; ++f) xv[f] = ((const float*)&ac[f])[q];

            const int sy = p / NGg;
            const int sx = p - sy * NGg;
            const float gxf = (float)sx, gyf = (float)sy;

            float pbx0[3], pby0[3], pbx1[3], pby1[3], pa[3], cf[3];
#pragma unroll
            for (int a = 0; a < 3; ++a) {
                const float px = sigm(xv[a*5+0] + bias[a*NCg+0]) + gxf;
                const float py = sigm(xv[a*5+1] + bias[a*NCg+1]) + gyf;
                const float pw = expf(xv[a*5+2] + bias[a*NCg+2]) * c_AW[a];
                const float ph = expf(xv[a*5+3] + bias[a*NCg+3]) * c_AH[a];
                cf[a]   = sigm(xv[a*5+4] + bias[a*NCg+4]);
                pbx0[a] = px - pw * 0.5f;  pby0[a] = py - ph * 0.5f;
                pbx1[a] = px + pw * 0.5f;  pby1[a] = py + ph * 0.5f;
                pa[a]   = pw * ph;
            }

            int mask = 0;
            for (int n = 0; n < NBOX; ++n) {
                const float bx0 = gb[n*8+0], by0 = gb[n*8+1];
                const float bx1 = gb[n*8+2], by1 = gb[n*8+3];
                const float gar = gb[n*8+4];
                const int cell  = __float_as_int(gb[n*8+5]);
                const int d = cell - p;
                if (d == 0)       mask |= 8;      // assigned, anchor 0
                if (d == NSp)     mask |= 16;     // anchor 1
                if (d == 2*NSp)   mask |= 32;     // anchor 2
                if (gar >= 0.f) {                 // block-uniform branch
#pragma unroll
                    for (int a = 0; a < 3; ++a) {
                        const float tlx = fmaxf(pbx0[a], bx0);
                        const float tly = fmaxf(pby0[a], by0);
                        const float brx = fminf(pbx1[a], bx1);
                        const float bry = fminf(pby1[a], by1);
                        const float dx = brx - tlx, dy = bry - tly;
                        const float inter = (dx > 0.f && dy > 0.f) ? dx * dy : 0.f;
                        // iou > 0.7  <=>  inter > 0.7*union   (no division)
                        if (inter > 0.7f * (pa[a] + gar - inter)) mask |= (1 << a);
                    }
                }
            }

#pragma unroll
            for (int a = 0; a < 3; ++a) {
                const bool ex = (mask & (1 << a)) != 0;
                const bool as = (mask & (8 << a)) != 0;
                const bool maskpre = hasB ? (!ex) : true;
                if (maskpre || as) {
                    const float c = cf[a];
                    lsum += as ? -safe_log(c) : -safe_log(1.f - c);
                }
            }
        }
    }

#pragma unroll
    for (int off = 32; off > 0; off >>= 1) lsum += __shfl_down(lsum, off);
    if (l == 0) wred[w] = lsum;
    __syncthreads();
    if (tid == 0) atomicAdd(&acc[2], wred[0] + wred[1] + wred[2] + wred[3]);

    // ---- finalize ticket --------------------------------------------------
    if (tid == 0) {
        __threadfence();
        const int v = atomicAdd(done, 1);
        if (v == TOTALL - 1) {
            const float xy = atomicAdd(&acc[0], 0.f);
            const float wh = atomicAdd(&acc[1], 0.f);
            const float ob = atomicAdd(&acc[2], 0.f);
            const float cl = atomicAdd(&acc[3], 0.f);
            out[0] = xy + wh + ob + cl;
            out[1] = xy; out[2] = wh; out[3] = ob; out[4] = cl;
        }
    }
}

extern "C" void kernel_launch(void* const* d_in, const int* in_sizes, int n_in,
                              void* d_out, int out_size, void* d_ws, size_t ws_size,
                              hipStream_t stream)
{
    const float* xin    = (const float*)d_in[0];
    const float* labels = (const float*)d_in[1];
    const float* W      = (const float*)d_in[2];
    const float* bias   = (const float*)d_in[3];

    char* ws = (char*)d_ws;
    float* acc    = (float*)(ws + ACC_OFF);
    int*   hasAny = (int*)  (ws + HAS_OFF);
    int*   done   = (int*)  (ws + DONE_OFF);
    float* Wt     = (float*)(ws + WT_OFF);
    float* gbox   = (float*)(ws + GB_OFF);
    float* gaux   = (float*)(ws + GA_OFF);
    int*   gint   = (int*)  (ws + GI_OFF);
    float* out    = (float*)d_out;

    k_labels<<<16, 256, 0, stream>>>(labels, W, Wt, gbox, gaux, gint, hasAny, acc, done);

    k_assigned<<<dim3(NB * NBOX), 256, 0, stream>>>(xin, W, bias, gaux, gint,
                                                    acc, done, out);

    k_main<<<dim3(GBLK, NB), 256, 0, stream>>>(xin, Wt, bias, gbox, hasAny,
                                               acc, done, out);
}

// Round 10
// 278.407 us; speedup vs baseline: 1.1265x; 1.1265x over previous
//
#include <hip/hip_runtime.h>
#include <math.h>
#include <stdint.h>

#define NB    16
#define NAg   3
#define NCg   85
#define NCLS  80
#define NGg   76
#define NSp   (NGg*NGg)     // 5776
#define NBOX  50
#define INCH  256
#define WPOS  256           // positions per wave (64 lanes x float4)
#define GBLK  ((NSp + WPOS - 1) / WPOS) // 23 GEMM blocks per batch
#define TOTALL (GBLK * NB + NB * NBOX)  // 368 + 800 = 1168 ticket blocks

// ws layout (bytes)
#define ACC_OFF  0                       // 8 floats  (loss accumulators)
#define HAS_OFF  32                      // 16 ints   (per-batch has_boxes flag)
#define DONE_OFF 96                      // 1 int     (last-block ticket)
#define WT_OFF   128                     // 256*16 floats = 16384 B (transposed W)
#define GB_OFF   (WT_OFF + 16384)        // NB*NBOX*8 floats = 25600 B (IoU boxes)
#define GA_OFF   (GB_OFF + 25600)        // NB*NBOX*8 floats = 25600 B (target aux)
#define GI_OFF   (GA_OFF + 25600)        // NB*NBOX*2 ints   =  6400 B (cell, cls)

__device__ __constant__ float c_AW[9] = {1.25f,2.0f,4.125f,3.75f,7.75f,7.375f,14.5f,19.5f,46.625f};
__device__ __constant__ float c_AH[9] = {1.625f,3.75f,2.875f,7.625f,5.625f,14.875f,11.25f,24.75f,40.75f};

__device__ __forceinline__ float safe_log(float p) {
    return fmaxf(logf(fmaxf(p, 1e-12f)), -100.0f);
}
__device__ __forceinline__ float sigm(float x) {
    return 1.0f / (1.0f + expf(-x));
}

// ---- Kernel 1: label processing + W transpose + acc/done init -------------
__global__ __launch_bounds__(256) void k_labels(
    const float* __restrict__ labels, const float* __restrict__ W,
    float* __restrict__ Wt, float* __restrict__ gbox, float* __restrict__ gaux,
    int* __restrict__ gint, int* __restrict__ hasAny, float* __restrict__ acc,
    int* __restrict__ done)
{
    const int b = blockIdx.x, tid = threadIdx.x;
    const int t = b * 256 + tid;

    // transposed weights: Wt[c*16 + f] = W[row(f)*INCH + c], f<15 (slot 15 pad)
    {
        const int c = t >> 4, f = t & 15;
        Wt[t] = (f < 15) ? W[((f / 5) * NCg + (f % 5)) * INCH + c] : 0.f;
    }
    if (b == 0 && tid < 8)  acc[tid] = 0.f;
    if (b == 0 && tid == 8) *done = 0;

    int valid = 0;
    if (tid < NBOX) {
        const int bt = b * NBOX + tid;
        const float* L = labels + (size_t)bt * 5;
        const float l0 = L[0], l1 = L[1], l2 = L[2], l3 = L[3], l4 = L[4];
        valid = (l0 + l1 + l2 + l3 + l4) > 0.f;

        const float gx = l1 * NGg, gy = l2 * NGg, gw = l3 * NGg, gh = l4 * NGg;

        int best = 0; float brr = -1.f;
#pragma unroll
        for (int k = 0; k < 9; k++) {
            float inter = fminf(gw, c_AW[k]) * fminf(gh, c_AH[k]);
            float uni   = gw*gh + c_AW[k]*c_AH[k] - inter;
            float r     = inter / uni;
            if (r > brr) { brr = r; best = k; }   // first max wins (argmax)
        }
        const int a = (best <= 2) ? best : -1;
        const int assign = valid && (a >= 0);
        const int a_safe = a < 0 ? 0 : (a > 2 ? 2 : a);

        const int gi = (int)floorf(gx), gj = (int)floorf(gy);
        const int inb = (gi >= 0) && (gi < NGg) && (gj >= 0) && (gj < NGg);
        const int cell = (assign && inb) ? (a * NSp + gj * NGg + gi) : -1;

        float* gb = gbox + (size_t)bt * 8;
        gb[0] = gx - gw * 0.5f;             // x0
        gb[1] = gy - gh * 0.5f;             // y0
        gb[2] = gx + gw * 0.5f;             // x1
        gb[3] = gy + gh * 0.5f;             // y1
        gb[4] = valid ? gw * gh : -1.f;     // area, <0 => skip in IoU
        gb[5] = __int_as_float(cell);       // assigned cell (-1 none)

        float* ga = gaux + (size_t)bt * 8;
        ga[0] = gx - floorf(gx);
        ga[1] = gy - floorf(gy);
        ga[2] = logf(gw / c_AW[a_safe] + 1e-16f);
        ga[3] = logf(gh / c_AH[a_safe] + 1e-16f);
        ga[4] = 2.f - gw * gh / (float)NSp;

        gint[bt*2 + 0] = cell;
        gint[bt*2 + 1] = (int)l0;
    }
    if (tid < 64) {
        const unsigned long long m = __ballot(valid != 0);
        if (tid == 0) hasAny[b] = (m != 0ULL) ? 1 : 0;
    }
}

// ---- Kernel 2: per-assigned-box xy/wh/cls losses --------------------------
__global__ __launch_bounds__(256) void k_assigned(
    const float* __restrict__ xin, const float* __restrict__ W,
    const float* __restrict__ bias, const float* __restrict__ gaux,
    const int* __restrict__ gint, float* __restrict__ acc,
    int* __restrict__ done, float* __restrict__ out)
{
    const int t = blockIdx.x;            // box id 0..799
    const int b = t / NBOX, n = t % NBOX;
    const int tid = threadIdx.x;

    __shared__ int   scell[NBOX];
    __shared__ float4 col4[64];
    __shared__ float  xsh[NCg];
    __shared__ float  sacc[3];

    if (tid < NBOX) scell[tid] = gint[(b * NBOX + tid) * 2];
    __syncthreads();

    const int cell = scell[n];
    bool win = (cell >= 0);              // block-uniform
    if (win)
        for (int n2 = n + 1; n2 < NBOX; ++n2)
            if (scell[n2] == cell) { win = false; break; }

    if (win) {
        const int a = cell / NSp, s = cell % NSp;
        const int o0 = a * NCg;

        ((float*)col4)[tid] = xin[((size_t)b * INCH + tid) * NSp + s];
        if (tid < 3) sacc[tid] = 0.f;
        __syncthreads();

        const int wid = tid >> 6, lane = tid & 63;
        for (int o = wid; o < NCg; o += 4) {
            const float4 wv = *(const float4*)&W[(size_t)(o0 + o) * INCH + lane * 4];
            const float4 cv = col4[lane];
            float p = wv.x*cv.x + wv.y*cv.y + wv.z*cv.z + wv.w*cv.w;
            for (int off = 32; off; off >>= 1) p += __shfl_down(p, off);
            if (lane == 0) xsh[o] = p + bias[o0 + o];
        }
        __syncthreads();

        if (tid < NCg) {
            const float* ga = gaux + (size_t)t * 8;
            const float sval = ga[4];
            const int gcls = gint[t*2 + 1];
            float val = xsh[tid];
            float term; int slot;
            if (tid < 2) {                       // xy BCE * sval
                float tgt = ga[tid];
                float p = sigm(val);
                term = -(tgt * safe_log(p) + (1.f - tgt) * safe_log(1.f - p)) * sval;
                slot = 0;
            } else if (tid < 4) {                // wh MSE * 0.5*sval
                float tgt = ga[tid];             // ga[2], ga[3]
                float d = val - tgt;
                term = 0.5f * sval * d * d;
                slot = 1;
            } else if (tid == 4) {               // conf handled in k_main
                term = 0.f; slot = 2;
            } else {                             // cls BCE
                float tgt = ((tid - 5) == gcls) ? 1.f : 0.f;
                float p = sigm(val);
                term = -(tgt * safe_log(p) + (1.f - tgt) * safe_log(1.f - p));
                slot = 2;
            }
            atomicAdd(&sacc[slot], term);
        }
        __syncthreads();
        if (tid == 0) {
            atomicAdd(&acc[0], sacc[0]);
            atomicAdd(&acc[1], sacc[1]);
            atomicAdd(&acc[3], sacc[2]);
        }
    }

    if (tid == 0) {
        __threadfence();
        const int v = atomicAdd(done, 1);
        if (v == TOTALL - 1) {
            const float xy = atomicAdd(&acc[0], 0.f);
            const float wh = atomicAdd(&acc[1], 0.f);
            const float ob = atomicAdd(&acc[2], 0.f);
            const float cl = atomicAdd(&acc[3], 0.f);
            out[0] = xy + wh + ob + cl;
            out[1] = xy; out[2] = wh; out[3] = ob; out[4] = cl;
        }
    }
}

// ---- Kernel 3: fused GEMM + decode + IoU + obj BCE ------------------------
// 64-thread (1-wave) blocks, grid (23,16). Wave owns 256 contiguous
// positions; channels consumed in 32 groups of 8 staged via
// global_load_lds into a 2x8KB LDS double-buffer with COUNTED vmcnt(8)
// (never 0 mid-loop) -> 8-16 1KB requests per wave continuously in
// flight, no VGPR staging, no __syncthreads (wave-private buffers).
__global__ __launch_bounds__(64) void k_main(
    const float* __restrict__ xin, const float* __restrict__ Wt,
    const float* __restrict__ bias, const float* __restrict__ gbox,
    const int* __restrict__ hasAny, float* __restrict__ acc,
    int* __restrict__ done, float* __restrict__ out)
{
    __shared__ __align__(16) float sbuf[2][8 * 256];   // 2 x 8KB

    const int bx  = blockIdx.x;
    const int b   = blockIdx.y;
    const int l   = threadIdx.x;          // lane 0..63
    const int pb  = bx * WPOS;

    float4 ac[15];
#pragma unroll
    for (int f = 0; f < 15; ++f) ac[f] = make_float4(0.f,0.f,0.f,0.f);

    const float* xp = xin + (size_t)b * INCH * NSp + pb;

    if (pb + WPOS <= NSp) {
        // ---- fast path: deep-pipelined LDS staging ------------------------
        // stage group g (channels 8g..8g+7) into sbuf[par]
        #define STAGE(g, par)                                                  \
        { _Pragma("unroll") for (int k = 0; k < 8; ++k) {                      \
            const float* gp = xp + (size_t)((g)*8 + k) * NSp + 4*l;            \
            __builtin_amdgcn_global_load_lds(                                  \
                (const __attribute__((address_space(1))) void*)gp,             \
                (__attribute__((address_space(3))) void*)&sbuf[par][k*256],    \
                16, 0, 0); } }

        STAGE(0, 0)
        STAGE(1, 1)
        for (int g = 0; g < 32; ++g) {
            // wait for group g only; keep later groups in flight
            if (g < 31) asm volatile("s_waitcnt vmcnt(8)" ::: "memory");
            else        asm volatile("s_waitcnt vmcnt(0)" ::: "memory");
            __builtin_amdgcn_sched_barrier(0);
            const int par = g & 1;
#pragma unroll
            for (int k = 0; k < 8; ++k) {
                const float4 v = *(const float4*)&sbuf[par][k*256 + 4*l];
                const float* wr = Wt + ((g*8 + k) << 4);   // block-uniform
#pragma unroll
                for (int f = 0; f < 15; ++f) {
                    const float wv = wr[f];
                    ac[f].x += wv * v.x;  ac[f].y += wv * v.y;
                    ac[f].z += wv * v.z;  ac[f].w += wv * v.w;
                }
            }
            if (g + 2 < 32) STAGE(g + 2, par)    // refill just-consumed buffer
        }
        #undef STAGE
    } else {
        // ---- tail block: plain guarded loads (no gload_lds OOB) -----------
        const bool lv = (pb + 4*l) < NSp;
        const float4 z = make_float4(0.f,0.f,0.f,0.f);
        const float* xq = xp + 4*l;
        for (int c0 = 0; c0 < INCH; c0 += 8) {
            float4 v[8];
#pragma unroll
            for (int k = 0; k < 8; ++k)
                v[k] = lv ? *(const float4*)(xq + (size_t)(c0 + k) * NSp) : z;
#pragma unroll
            for (int k = 0; k < 8; ++k) {
                const float* wr = Wt + ((c0 + k) << 4);
#pragma unroll
                for (int f = 0; f < 15; ++f) {
                    const float wv = wr[f];
                    ac[f].x += wv * v[k].x;  ac[f].y += wv * v[k].y;
                    ac[f].z += wv * v[k].z;  ac[f].w += wv * v[k].w;
                }
            }
        }
    }

    // ---- decode + IoU + obj BCE: thread owns positions pb+4l .. pb+4l+3 ---
    float lsum = 0.f;
    if ((pb + 4*l) < NSp) {
        const bool hasB = hasAny[b] != 0;
        const float* gb = gbox + (size_t)b * NBOX * 8;
#pragma unroll
        for (int q = 0; q < 4; ++q) {
            const int p = pb + 4*l + q;
            float xv[15];
#pragma unroll
            for (int f = 0; f < 15; ++f) xv[f] = ((const float*)&ac[f])[q];

            const int sy = p / NGg;
            const int sx = p - sy * NGg;
            const float gxf = (float)sx, gyf = (float)sy;

            float pbx0[3], pby0[3], pbx1[3], pby1[3], pa[3], cf[3];
#pragma unroll
            for (int a = 0; a < 3; ++a) {
                const float px = sigm(xv[a*5+0] + bias[a*NCg+0]) + gxf;
                const float py = sigm(xv[a*5+1] + bias[a*NCg+1]) + gyf;
                const float pw = expf(xv[a*5+2] + bias[a*NCg+2]) * c_AW[a];
                const float ph = expf(xv[a*5+3] + bias[a*NCg+3]) * c_AH[a];
                cf[a]   = sigm(xv[a*5+4] + bias[a*NCg+4]);
                pbx0[a] = px - pw * 0.5f;  pby0[a] = py - ph * 0.5f;
                pbx1[a] = px + pw * 0.5f;  pby1[a] = py + ph * 0.5f;
                pa[a]   = pw * ph;
            }

            int mask = 0;
            for (int n = 0; n < NBOX; ++n) {
                const float bx0 = gb[n*8+0], by0 = gb[n*8+1];
                const float bx1 = gb[n*8+2], by1 = gb[n*8+3];
                const float gar = gb[n*8+4];
                const int cell  = __float_as_int(gb[n*8+5]);
                const int d = cell - p;
                if (d == 0)       mask |= 8;      // assigned, anchor 0
                if (d == NSp)     mask |= 16;     // anchor 1
                if (d == 2*NSp)   mask |= 32;     // anchor 2
                if (gar >= 0.f) {                 // wave-uniform branch
#pragma unroll
                    for (int a = 0; a < 3; ++a) {
                        const float tlx = fmaxf(pbx0[a], bx0);
                        const float tly = fmaxf(pby0[a], by0);
                        const float brx = fminf(pbx1[a], bx1);
                        const float bry = fminf(pby1[a], by1);
                        const float dx = brx - tlx, dy = bry - tly;
                        const float inter = (dx > 0.f && dy > 0.f) ? dx * dy : 0.f;
                        // iou > 0.7  <=>  inter > 0.7*union   (no division)
                        if (inter > 0.7f * (pa[a] + gar - inter)) mask |= (1 << a);
                    }
                }
            }

#pragma unroll
            for (int a = 0; a < 3; ++a) {
                const bool ex = (mask & (1 << a)) != 0;
                const bool as = (mask & (8 << a)) != 0;
                const bool maskpre = hasB ? (!ex) : true;
                if (maskpre || as) {
                    const float c = cf[a];
                    lsum += as ? -safe_log(c) : -safe_log(1.f - c);
                }
            }
        }
    }

#pragma unroll
    for (int off = 32; off > 0; off >>= 1) lsum += __shfl_down(lsum, off);
    if (l == 0) atomicAdd(&acc[2], lsum);

    // ---- finalize ticket --------------------------------------------------
    if (l == 0) {
        __threadfence();
        const int v = atomicAdd(done, 1);
        if (v == TOTALL - 1) {
            const float xy = atomicAdd(&acc[0], 0.f);
            const float wh = atomicAdd(&acc[1], 0.f);
            const float ob = atomicAdd(&acc[2], 0.f);
            const float cl = atomicAdd(&acc[3], 0.f);
            out[0] = xy + wh + ob + cl;
            out[1] = xy; out[2] = wh; out[3] = ob; out[4] = cl;
        }
    }
}

extern "C" void kernel_launch(void* const* d_in, const int* in_sizes, int n_in,
                              void* d_out, int out_size, void* d_ws, size_t ws_size,
                              hipStream_t stream)
{
    const float* xin    = (const float*)d_in[0];
    const float* labels = (const float*)d_in[1];
    const float* W      = (const float*)d_in[2];
    const float* bias   = (const float*)d_in[3];

    char* ws = (char*)d_ws;
    float* acc    = (float*)(ws + ACC_OFF);
    int*   hasAny = (int*)  (ws + HAS_OFF);
    int*   done   = (int*)  (ws + DONE_OFF);
    float* Wt     = (float*)(ws + WT_OFF);
    float* gbox   = (float*)(ws + GB_OFF);
    float* gaux   = (float*)(ws + GA_OFF);
    int*   gint   = (int*)  (ws + GI_OFF);
    float* out    = (float*)d_out;

    k_labels<<<16, 256, 0, stream>>>(labels, W, Wt, gbox, gaux, gint, hasAny, acc, done);

    k_assigned<<<dim3(NB * NBOX), 256, 0, stream>>>(xin, W, bias, gaux, gint,
                                                    acc, done, out);

    k_main<<<dim3(GBLK, NB), 64, 0, stream>>>(xin, Wt, bias, gbox, hasAny,
                                              acc, done, out);
}

// Round 11
// 209.209 us; speedup vs baseline: 1.4991x; 1.3308x over previous
//
#include <hip/hip_runtime.h>
#include <math.h>

#define NB    16
#define NAg   3
#define NCg   85
#define NCLS  80
#define NGg   76
#define NSp   (NGg*NGg)     // 5776
#define NBOX  50
#define INCH  256
#define SPB   256           // spatial positions per GEMM block
#define GBLK  ((NSp + SPB - 1) / SPB)   // 23 GEMM blocks per batch
#define GXDIM (GBLK + NBOX)             // 73: x<23 GEMM path, x>=23 box path
#define TOTBLK (GXDIM * NB)             // 1168 ticket blocks

// ws layout (bytes)
#define ACC_OFF  0                       // 8 floats  (loss accumulators)
#define HAS_OFF  32                      // 16 ints   (per-batch has_boxes flag)
#define DONE_OFF 96                      // 1 int     (last-block ticket)
#define WT_OFF   128                     // 256*16 floats = 16384 B (transposed W)
#define GB_OFF   (WT_OFF + 16384)        // NB*NBOX*8 floats = 25600 B (IoU boxes)
#define GA_OFF   (GB_OFF + 25600)        // NB*NBOX*8 floats = 25600 B (target aux)
#define GI_OFF   (GA_OFF + 25600)        // NB*NBOX*2 ints   =  6400 B (cell, cls)

__device__ __constant__ float c_AW[9] = {1.25f,2.0f,4.125f,3.75f,7.75f,7.375f,14.5f,19.5f,46.625f};
__device__ __constant__ float c_AH[9] = {1.625f,3.75f,2.875f,7.625f,5.625f,14.875f,11.25f,24.75f,40.75f};

__device__ __forceinline__ float safe_log(float p) {
    return fmaxf(logf(fmaxf(p, 1e-12f)), -100.0f);
}
__device__ __forceinline__ float sigm(float x) {
    return 1.0f / (1.0f + expf(-x));
}

// ---- Kernel 1: label processing + W transpose + acc/done init -------------
__global__ __launch_bounds__(256) void k_labels(
    const float* __restrict__ labels, const float* __restrict__ W,
    float* __restrict__ Wt, float* __restrict__ gbox, float* __restrict__ gaux,
    int* __restrict__ gint, int* __restrict__ hasAny, float* __restrict__ acc,
    int* __restrict__ done)
{
    const int b = blockIdx.x, tid = threadIdx.x;
    const int t = b * 256 + tid;

    // transposed weights: Wt[c*16 + f] = W[row(f)*INCH + c], f<15 (slot 15 pad)
    {
        const int c = t >> 4, f = t & 15;
        Wt[t] = (f < 15) ? W[((f / 5) * NCg + (f % 5)) * INCH + c] : 0.f;
    }
    if (b == 0 && tid < 8)  acc[tid] = 0.f;
    if (b == 0 && tid == 8) *done = 0;

    int valid = 0;
    if (tid < NBOX) {
        const int bt = b * NBOX + tid;
        const float* L = labels + (size_t)bt * 5;
        const float l0 = L[0], l1 = L[1], l2 = L[2], l3 = L[3], l4 = L[4];
        valid = (l0 + l1 + l2 + l3 + l4) > 0.f;

        const float gx = l1 * NGg, gy = l2 * NGg, gw = l3 * NGg, gh = l4 * NGg;

        int best = 0; float brr = -1.f;
#pragma unroll
        for (int k = 0; k < 9; k++) {
            float inter = fminf(gw, c_AW[k]) * fminf(gh, c_AH[k]);
            float uni   = gw*gh + c_AW[k]*c_AH[k] - inter;
            float r     = inter / uni;
            if (r > brr) { brr = r; best = k; }   // first max wins (argmax)
        }
        const int a = (best <= 2) ? best : -1;
        const int assign = valid && (a >= 0);
        const int a_safe = a < 0 ? 0 : (a > 2 ? 2 : a);

        const int gi = (int)floorf(gx), gj = (int)floorf(gy);
        const int inb = (gi >= 0) && (gi < NGg) && (gj >= 0) && (gj < NGg);
        const int cell = (assign && inb) ? (a * NSp + gj * NGg + gi) : -1;

        float* gb = gbox + (size_t)bt * 8;
        gb[0] = gx - gw * 0.5f;             // x0
        gb[1] = gy - gh * 0.5f;             // y0
        gb[2] = gx + gw * 0.5f;             // x1
        gb[3] = gy + gh * 0.5f;             // y1
        gb[4] = valid ? gw * gh : -1.f;     // area, <0 => skip in IoU
        gb[5] = __int_as_float(cell);       // assigned cell (-1 none)

        float* ga = gaux + (size_t)bt * 8;
        ga[0] = gx - floorf(gx);
        ga[1] = gy - floorf(gy);
        ga[2] = logf(gw / c_AW[a_safe] + 1e-16f);
        ga[3] = logf(gh / c_AH[a_safe] + 1e-16f);
        ga[4] = 2.f - gw * gh / (float)NSp;

        gint[bt*2 + 0] = cell;
        gint[bt*2 + 1] = (int)l0;
    }
    if (tid < 64) {
        const unsigned long long m = __ballot(valid != 0);
        if (tid == 0) hasAny[b] = (m != 0ULL) ? 1 : 0;
    }
}

// ---- Kernel 2: mega-kernel, 30.7KB LDS -> 5 blocks/CU -> all 1168 resident
// grid (73,16). bx<23 : GEMM+decode+IoU+obj (2-way channel split, 512B reqs)
//               bx>=23: per-assigned-box xy/wh/cls losses
__global__ __launch_bounds__(256) void k_mega(
    const float* __restrict__ xin, const float* __restrict__ Wt,
    const float* __restrict__ W, const float* __restrict__ bias,
    const float* __restrict__ gbox, const float* __restrict__ gaux,
    const int* __restrict__ gint, const int* __restrict__ hasAny,
    float* __restrict__ acc, int* __restrict__ done, float* __restrict__ out)
{
    __shared__ __align__(16) float smem[2*15*SPB + 4];   // 30,736 B

    const int bx  = blockIdx.x;
    const int b   = blockIdx.y;
    const int tid = threadIdx.x;

    if (bx < GBLK) {
        // ================= GEMM / decode / IoU / obj-BCE path ==============
        float (*part)[15][SPB] = (float (*)[15][SPB])smem;   // [2][15][256]
        float* wred = smem + 2*15*SPB;                       // 4 floats

        const int w  = tid >> 6, l = tid & 63;
        const int wu = __builtin_amdgcn_readfirstlane(w);
        const int posHalf = wu >> 1;          // waves 0,1 -> pos 0-127; 2,3 -> 128-255
        const int chBase  = (wu & 1) << 7;    // waves even -> ch 0-127; odd -> 128-255
        const int pb  = bx * SPB;
        const int pOff = (posHalf << 7) + 2*l;      // 0..254 (even)
        const int p0  = pb + pOff;
        const bool live = p0 < NSp;           // p0 even, NSp even -> float2 safe

        float2 a2[15];
#pragma unroll
        for (int f = 0; f < 15; ++f) a2[f] = make_float2(0.f, 0.f);

        const float* xp = xin + ((size_t)b * INCH + chBase) * NSp + p0;
        const float* wp = Wt + (chBase << 4);

        if (live) {
            for (int c0 = 0; c0 < 128; c0 += 8) {
                float2 v[8];
#pragma unroll
                for (int k = 0; k < 8; ++k)
                    v[k] = *(const float2*)(xp + (size_t)(c0 + k) * NSp);
#pragma unroll
                for (int k = 0; k < 8; ++k) {
                    const float* wr = wp + ((c0 + k) << 4);   // wave-uniform
#pragma unroll
                    for (int f = 0; f < 15; ++f) {
                        const float wv = wr[f];
                        a2[f].x += wv * v[k].x;
                        a2[f].y += wv * v[k].y;
                    }
                }
            }
        }
#pragma unroll
        for (int f = 0; f < 15; ++f)
            *(float2*)&part[wu & 1][f][pOff] = a2[f];   // zeros when !live
        __syncthreads();

        // ---- decode + IoU + obj BCE: thread tid owns position pb+tid ------
        float lsum = 0.f;
        const int p = pb + tid;
        if (p < NSp) {
            float xv[15];
#pragma unroll
            for (int f = 0; f < 15; ++f)
                xv[f] = part[0][f][tid] + part[1][f][tid];

            const int sy = p / NGg;
            const int sx = p - sy * NGg;
            const float gxf = (float)sx, gyf = (float)sy;

            float pbx0[3], pby0[3], pbx1[3], pby1[3], pa[3], cf[3];
#pragma unroll
            for (int a = 0; a < 3; ++a) {
                const float px = sigm(xv[a*5+0] + bias[a*NCg+0]) + gxf;
                const float py = sigm(xv[a*5+1] + bias[a*NCg+1]) + gyf;
                const float pw = expf(xv[a*5+2] + bias[a*NCg+2]) * c_AW[a];
                const float ph = expf(xv[a*5+3] + bias[a*NCg+3]) * c_AH[a];
                cf[a]   = sigm(xv[a*5+4] + bias[a*NCg+4]);
                pbx0[a] = px - pw * 0.5f;  pby0[a] = py - ph * 0.5f;
                pbx1[a] = px + pw * 0.5f;  pby1[a] = py + ph * 0.5f;
                pa[a]   = pw * ph;
            }

            int mask = 0;
            const float* gb = gbox + (size_t)b * NBOX * 8;
            for (int n = 0; n < NBOX; ++n) {
                const float bx0 = gb[n*8+0], by0 = gb[n*8+1];
                const float bx1 = gb[n*8+2], by1 = gb[n*8+3];
                const float gar = gb[n*8+4];
                const int cell  = __float_as_int(gb[n*8+5]);
                const int d = cell - p;
                if (d == 0)       mask |= 8;      // assigned, anchor 0
                if (d == NSp)     mask |= 16;     // anchor 1
                if (d == 2*NSp)   mask |= 32;     // anchor 2
                if (gar >= 0.f) {                 // block-uniform branch
#pragma unroll
                    for (int a = 0; a < 3; ++a) {
                        const float tlx = fmaxf(pbx0[a], bx0);
                        const float tly = fmaxf(pby0[a], by0);
                        const float brx = fminf(pbx1[a], bx1);
                        const float bry = fminf(pby1[a], by1);
                        const float dx = brx - tlx, dy = bry - tly;
                        const float inter = (dx > 0.f && dy > 0.f) ? dx * dy : 0.f;
                        // iou > 0.7  <=>  inter > 0.7*union   (no division)
                        if (inter > 0.7f * (pa[a] + gar - inter)) mask |= (1 << a);
                    }
                }
            }

            const bool hasB = hasAny[b] != 0;
#pragma unroll
            for (int a = 0; a < 3; ++a) {
                const bool ex = (mask & (1 << a)) != 0;
                const bool as = (mask & (8 << a)) != 0;
                const bool maskpre = hasB ? (!ex) : true;
                if (maskpre || as) {
                    const float c = cf[a];
                    lsum += as ? -safe_log(c) : -safe_log(1.f - c);
                }
            }
        }

#pragma unroll
        for (int off = 32; off > 0; off >>= 1) lsum += __shfl_down(lsum, off);
        if (l == 0) wred[w] = lsum;
        __syncthreads();
        if (tid == 0) atomicAdd(&acc[2], wred[0] + wred[1] + wred[2] + wred[3]);

    } else {
        // ================= per-assigned-box path ===========================
        int*    scell = (int*)smem;                 // 50 ints
        float4* col4  = (float4*)(smem + 64);       // 64 float4
        float*  xsh   = smem + 64 + 256;            // 85 floats
        float*  sacc  = smem + 64 + 256 + 96;       // 3 floats

        const int n = bx - GBLK;                    // box 0..49
        const int t = b * NBOX + n;

        if (tid < NBOX) scell[tid] = gint[(b * NBOX + tid) * 2];
        __syncthreads();

        const int cell = scell[n];
        bool win = (cell >= 0);                     // block-uniform
        if (win)
            for (int n2 = n + 1; n2 < NBOX; ++n2)
                if (scell[n2] == cell) { win = false; break; }

        if (win) {                                  // block-uniform branch
            const int a = cell / NSp, s = cell % NSp;
            const int o0 = a * NCg;

            ((float*)col4)[tid] = xin[((size_t)b * INCH + tid) * NSp + s];
            if (tid < 3) sacc[tid] = 0.f;
            __syncthreads();

            const int wid = tid >> 6, lane = tid & 63;
            for (int o = wid; o < NCg; o += 4) {
                const float4 wv = *(const float4*)&W[(size_t)(o0 + o) * INCH + lane * 4];
                const float4 cv = col4[lane];
                float p = wv.x*cv.x + wv.y*cv.y + wv.z*cv.z + wv.w*cv.w;
                for (int off = 32; off; off >>= 1) p += __shfl_down(p, off);
                if (lane == 0) xsh[o] = p + bias[o0 + o];
            }
            __syncthreads();

            if (tid < NCg) {
                const float* ga = gaux + (size_t)t * 8;
                const float sval = ga[4];
                const int gcls = gint[t*2 + 1];
                float val = xsh[tid];
                float term; int slot;
                if (tid < 2) {                       // xy BCE * sval
                    float tgt = ga[tid];
                    float pp = sigm(val);
                    term = -(tgt * safe_log(pp) + (1.f - tgt) * safe_log(1.f - pp)) * sval;
                    slot = 0;
                } else if (tid < 4) {                // wh MSE * 0.5*sval
                    float tgt = ga[tid];             // ga[2], ga[3]
                    float d = val - tgt;
                    term = 0.5f * sval * d * d;
                    slot = 1;
                } else if (tid == 4) {               // conf handled in GEMM path
                    term = 0.f; slot = 2;
                } else {                             // cls BCE
                    float tgt = ((tid - 5) == gcls) ? 1.f : 0.f;
                    float pp = sigm(val);
                    term = -(tgt * safe_log(pp) + (1.f - tgt) * safe_log(1.f - pp));
                    slot = 2;
                }
                atomicAdd(&sacc[slot], term);
            }
            __syncthreads();
            if (tid == 0) {
                atomicAdd(&acc[0], sacc[0]);
                atomicAdd(&acc[1], sacc[1]);
                atomicAdd(&acc[3], sacc[2]);
            }
        }
    }

    // ================= finalize ticket =====================================
    __syncthreads();
    if (tid == 0) {
        __threadfence();
        const int v = atomicAdd(done, 1);
        if (v == TOTBLK - 1) {
            const float xy = atomicAdd(&acc[0], 0.f);
            const float wh = atomicAdd(&acc[1], 0.f);
            const float ob = atomicAdd(&acc[2], 0.f);
            const float cl = atomicAdd(&acc[3], 0.f);
            out[0] = xy + wh + ob + cl;
            out[1] = xy; out[2] = wh; out[3] = ob; out[4] = cl;
        }
    }
}

extern "C" void kernel_launch(void* const* d_in, const int* in_sizes, int n_in,
                              void* d_out, int out_size, void* d_ws, size_t ws_size,
                              hipStream_t stream)
{
    const float* xin    = (const float*)d_in[0];
    const float* labels = (const float*)d_in[1];
    const float* W      = (const float*)d_in[2];
    const float* bias   = (const float*)d_in[3];

    char* ws = (char*)d_ws;
    float* acc    = (float*)(ws + ACC_OFF);
    int*   hasAny = (int*)  (ws + HAS_OFF);
    int*   done   = (int*)  (ws + DONE_OFF);
    float* Wt     = (float*)(ws + WT_OFF);
    float* gbox   = (float*)(ws + GB_OFF);
    float* gaux   = (float*)(ws + GA_OFF);
    int*   gint   = (int*)  (ws + GI_OFF);
    float* out    = (float*)d_out;

    k_labels<<<16, 256, 0, stream>>>(labels, W, Wt, gbox, gaux, gint, hasAny, acc, done);

    k_mega<<<dim3(GXDIM, NB), 256, 0, stream>>>(xin, Wt, W, bias, gbox, gaux,
                                                gint, hasAny, acc, done, out);
}

// Round 12
// 203.842 us; speedup vs baseline: 1.5386x; 1.0263x over previous
//
#include <hip/hip_runtime.h>
#include <math.h>

#define NB    16
#define NAg   3
#define NCg   85
#define NCLS  80
#define NGg   76
#define NSp   (NGg*NGg)     // 5776
#define NBOX  50
#define INCH  256
#define NG2   (NSp/2)       // 2888 float2 groups
#define SPB   128           // spatial positions per block
#define GPB   64            // float2 groups per block
#define GBLK  ((NSp + SPB - 1) / SPB)   // 46 blocks per batch
#define TOTBLK (GBLK * NB)              // 736
#define NWCAP 4             // in-stream captured wins per block (rest: fallback)

// ws layout (bytes)
#define ACC_OFF  0                       // 8 floats  (loss accumulators)
#define HAS_OFF  32                      // 16 ints   (per-batch has_boxes flag)
#define DONE_OFF 96                      // 1 int     (last-block ticket)
#define WT_OFF   128                     // 256*16 floats = 16384 B (transposed W)
#define GB_OFF   (WT_OFF + 16384)        // NB*NBOX*8 floats = 25600 B (IoU boxes)
#define GA_OFF   (GB_OFF + 25600)        // NB*NBOX*8 floats = 25600 B (target aux)
#define GI_OFF   (GA_OFF + 25600)        // NB*NBOX*2 ints   =  6400 B (cell, cls)

__device__ __constant__ float c_AW[9] = {1.25f,2.0f,4.125f,3.75f,7.75f,7.375f,14.5f,19.5f,46.625f};
__device__ __constant__ float c_AH[9] = {1.625f,3.75f,2.875f,7.625f,5.625f,14.875f,11.25f,24.75f,40.75f};

__device__ __forceinline__ float safe_log(float p) {
    return fmaxf(logf(fmaxf(p, 1e-12f)), -100.0f);
}
__device__ __forceinline__ float sigm(float x) {
    return 1.0f / (1.0f + expf(-x));
}

// ---- Kernel 1: label processing + W transpose + acc/done init -------------
__global__ __launch_bounds__(256) void k_labels(
    const float* __restrict__ labels, const float* __restrict__ W,
    float* __restrict__ Wt, float* __restrict__ gbox, float* __restrict__ gaux,
    int* __restrict__ gint, int* __restrict__ hasAny, float* __restrict__ acc,
    int* __restrict__ done)
{
    const int b = blockIdx.x, tid = threadIdx.x;
    const int t = b * 256 + tid;

    // transposed weights: Wt[c*16 + f] = W[row(f)*INCH + c], f<15 (slot 15 pad)
    {
        const int c = t >> 4, f = t & 15;
        Wt[t] = (f < 15) ? W[((f / 5) * NCg + (f % 5)) * INCH + c] : 0.f;
    }
    if (b == 0 && tid < 8)  acc[tid] = 0.f;
    if (b == 0 && tid == 8) *done = 0;

    int valid = 0;
    if (tid < NBOX) {
        const int bt = b * NBOX + tid;
        const float* L = labels + (size_t)bt * 5;
        const float l0 = L[0], l1 = L[1], l2 = L[2], l3 = L[3], l4 = L[4];
        valid = (l0 + l1 + l2 + l3 + l4) > 0.f;

        const float gx = l1 * NGg, gy = l2 * NGg, gw = l3 * NGg, gh = l4 * NGg;

        int best = 0; float brr = -1.f;
#pragma unroll
        for (int k = 0; k < 9; k++) {
            float inter = fminf(gw, c_AW[k]) * fminf(gh, c_AH[k]);
            float uni   = gw*gh + c_AW[k]*c_AH[k] - inter;
            float r     = inter / uni;
            if (r > brr) { brr = r; best = k; }   // first max wins (argmax)
        }
        const int a = (best <= 2) ? best : -1;
        const int assign = valid && (a >= 0);
        const int a_safe = a < 0 ? 0 : (a > 2 ? 2 : a);

        const int gi = (int)floorf(gx), gj = (int)floorf(gy);
        const int inb = (gi >= 0) && (gi < NGg) && (gj >= 0) && (gj < NGg);
        const int cell = (assign && inb) ? (a * NSp + gj * NGg + gi) : -1;

        float* gb = gbox + (size_t)bt * 8;
        gb[0] = gx - gw * 0.5f;             // x0
        gb[1] = gy - gh * 0.5f;             // y0
        gb[2] = gx + gw * 0.5f;             // x1
        gb[3] = gy + gh * 0.5f;             // y1
        gb[4] = valid ? gw * gh : -1.f;     // area, <0 => skip in IoU
        gb[5] = __int_as_float(cell);       // assigned cell (-1 none)

        float* ga = gaux + (size_t)bt * 8;
        ga[0] = gx - floorf(gx);
        ga[1] = gy - floorf(gy);
        ga[2] = logf(gw / c_AW[a_safe] + 1e-16f);
        ga[3] = logf(gh / c_AH[a_safe] + 1e-16f);
        ga[4] = 2.f - gw * gh / (float)NSp;

        gint[bt*2 + 0] = cell;
        gint[bt*2 + 1] = (int)l0;
    }
    if (tid < 64) {
        const unsigned long long m = __ballot(valid != 0);
        if (tid == 0) hasAny[b] = (m != 0ULL) ? 1 : 0;
    }
}

// ---- Kernel 2: fused GEMM + decode + IoU + obj BCE + in-stream box loss ---
// grid (46,16), 256 thr. GEMM = R3's fastest shape (float2, 4-way ch split).
// Winning cells inside this block's 128 positions get their 256-ch input
// column CAPTURED during the GEMM stream (no gather); xy/wh come from the
// existing 15-output buffer; cls via 80x256 GEMV from LDS vs L2-hot W.
__global__ __launch_bounds__(256) void k_mega(
    const float* __restrict__ xin, const float* __restrict__ Wt,
    const float* __restrict__ W, const float* __restrict__ bias,
    const float* __restrict__ gbox, const float* __restrict__ gaux,
    const int* __restrict__ gint, const int* __restrict__ hasAny,
    float* __restrict__ acc, int* __restrict__ done, float* __restrict__ out)
{
    __shared__ float2 buf[4][15][GPB];                    // 30,720 B
    __shared__ __align__(16) float cls_col[NWCAP][256];   //  4,096 B
    __shared__ int   scell[NBOX];
    __shared__ int   winf[NBOX];
    __shared__ int   wlN[NBOX], wlS[NBOX];
    __shared__ int   nwinS;
    __shared__ float xsh[NCg];
    __shared__ float sacc[3];
    __shared__ float wred[2];

    const int bx  = blockIdx.x;
    const int b   = blockIdx.y;
    const int tid = threadIdx.x;
    const int w   = tid >> 6, l = tid & 63;
    const int wu  = __builtin_amdgcn_readfirstlane(w);
    const int pb  = bx * SPB;

    // ============ phase 0: win list for this block's position range ========
    if (tid < NBOX) scell[tid] = gint[(b * NBOX + tid) * 2];
    __syncthreads();
    if (tid < NBOX) {
        const int cell = scell[tid];
        int f = (cell >= 0);
        for (int n2 = tid + 1; n2 < NBOX; ++n2)
            if (scell[n2] == cell) { f = 0; break; }   // last-index-wins
        winf[tid] = f;
    }
    __syncthreads();
    if (tid == 0) {
        int c = 0;
        for (int n = 0; n < NBOX; ++n) {
            if (winf[n]) {
                const int sw = scell[n] % NSp;
                if (sw >= pb && sw < pb + SPB) { wlN[c] = n; wlS[c] = sw; ++c; }
            }
        }
        nwinS = c;
    }
    __syncthreads();

    const int nwin = nwinS;
    int lwj[NWCAP], eej[NWCAP];
#pragma unroll
    for (int j = 0; j < NWCAP; ++j) {
        const int sw = (j < nwin) ? wlS[j] : pb;
        lwj[j] = (sw - pb) >> 1;
        eej[j] = sw & 1;
    }

    // ============ phase 1: GEMM (R3 shape) + in-stream capture =============
    const int G   = bx * GPB + l;
    const bool liveG = (G < NG2);

    float2 a2[15];
#pragma unroll
    for (int f = 0; f < 15; ++f) a2[f] = make_float2(0.f, 0.f);

    if (liveG) {
        const float* xp = xin + ((size_t)b * INCH + (wu << 6)) * NSp + (G << 1);
        const float* wp = Wt + ((wu << 6) << 4);
#pragma unroll 2
        for (int c0 = 0; c0 < 64; c0 += 8) {
            float2 v[8];
#pragma unroll
            for (int k = 0; k < 8; ++k)
                v[k] = *(const float2*)(xp + (size_t)(c0 + k) * NSp);
#pragma unroll
            for (int k = 0; k < 8; ++k) {
                const float* wr = wp + ((c0 + k) << 4);   // wave-uniform
#pragma unroll
                for (int f = 0; f < 15; ++f) {
                    a2[f].x += wr[f] * v[k].x;
                    a2[f].y += wr[f] * v[k].y;
                }
            }
            // capture winning columns (this wave's channel quarter)
#pragma unroll
            for (int j = 0; j < NWCAP; ++j) {
                if (j < nwin && l == lwj[j]) {
#pragma unroll
                    for (int k = 0; k < 8; ++k)
                        cls_col[j][(wu << 6) + c0 + k] = eej[j] ? v[k].y : v[k].x;
                }
            }
        }
    }
#pragma unroll
    for (int f = 0; f < 15; ++f) buf[w][f][l] = a2[f];
    __syncthreads();

    // ============ phase 2: decode + IoU + obj BCE (R3 verbatim) ============
    float lsum = 0.f;
    const int p = pb + tid;
    if (tid < SPB && p < NSp) {
        const int g = tid >> 1, e = tid & 1;
        float xv[15];
#pragma unroll
        for (int f = 0; f < 15; ++f) {
            xv[f] = ((const float*)&buf[0][f][g])[e]
                  + ((const float*)&buf[1][f][g])[e]
                  + ((const float*)&buf[2][f][g])[e]
                  + ((const float*)&buf[3][f][g])[e];
        }

        const int sy = p / NGg;
        const int sx = p - sy * NGg;
        const float gxf = (float)sx, gyf = (float)sy;

        float pbx0[3], pby0[3], pbx1[3], pby1[3], pa[3], cf[3];
#pragma unroll
        for (int a = 0; a < 3; ++a) {
            const float px = sigm(xv[a*5+0] + bias[a*NCg+0]) + gxf;
            const float py = sigm(xv[a*5+1] + bias[a*NCg+1]) + gyf;
            const float pw = expf(xv[a*5+2] + bias[a*NCg+2]) * c_AW[a];
            const float ph = expf(xv[a*5+3] + bias[a*NCg+3]) * c_AH[a];
            cf[a]   = sigm(xv[a*5+4] + bias[a*NCg+4]);
            pbx0[a] = px - pw * 0.5f;  pby0[a] = py - ph * 0.5f;
            pbx1[a] = px + pw * 0.5f;  pby1[a] = py + ph * 0.5f;
            pa[a]   = pw * ph;
        }

        int mask = 0;
        const float* gb = gbox + (size_t)b * NBOX * 8;
        for (int n = 0; n < NBOX; ++n) {
            const float bx0 = gb[n*8+0], by0 = gb[n*8+1];
            const float bx1 = gb[n*8+2], by1 = gb[n*8+3];
            const float gar = gb[n*8+4];
            const int cell  = __float_as_int(gb[n*8+5]);
            const int d = cell - p;
            if (d == 0)       mask |= 8;      // assigned, anchor 0
            if (d == NSp)     mask |= 16;     // anchor 1
            if (d == 2*NSp)   mask |= 32;     // anchor 2
            if (gar >= 0.f) {                 // block-uniform branch
#pragma unroll
                for (int a = 0; a < 3; ++a) {
                    const float tlx = fmaxf(pbx0[a], bx0);
                    const float tly = fmaxf(pby0[a], by0);
                    const float brx = fminf(pbx1[a], bx1);
                    const float bry = fminf(pby1[a], by1);
                    const float dx = brx - tlx, dy = bry - tly;
                    const float inter = (dx > 0.f && dy > 0.f) ? dx * dy : 0.f;
                    // iou > 0.7  <=>  inter > 0.7*union   (no division)
                    if (inter > 0.7f * (pa[a] + gar - inter)) mask |= (1 << a);
                }
            }
        }

        const bool hasB = hasAny[b] != 0;
#pragma unroll
        for (int a = 0; a < 3; ++a) {
            const bool ex = (mask & (1 << a)) != 0;
            const bool as = (mask & (8 << a)) != 0;
            const bool maskpre = hasB ? (!ex) : true;
            if (maskpre || as) {
                const float c = cf[a];
                lsum += as ? -safe_log(c) : -safe_log(1.f - c);
            }
        }
    }

#pragma unroll
    for (int off = 32; off > 0; off >>= 1) lsum += __shfl_down(lsum, off);
    if (w < 2 && l == 0) wred[w] = lsum;
    __syncthreads();
    if (tid == 0) atomicAdd(&acc[2], wred[0] + wred[1]);

    // ============ phase 3: box losses for this block's wins ================
    for (int j = 0; j < nwin; ++j) {          // nwin block-uniform
        __syncthreads();                      // xsh/sacc reuse fence
        const int n    = wlN[j];
        const int cell = scell[n];
        const int a    = cell / NSp;
        const int sw   = cell % NSp;
        const int o0   = a * NCg;
        const int t    = b * NBOX + n;
        const int pp   = sw - pb;
        const int g    = pp >> 1, e = pp & 1;

        if (j >= NWCAP) {                     // rare fallback: direct gather
            cls_col[0][tid] = xin[((size_t)b * INCH + tid) * NSp + sw];
            __syncthreads();
        }
        const float* col = cls_col[j < NWCAP ? j : 0];

        // cls GEMV: 80 outputs x 256 channels (W rows L2-hot)
        for (int o2 = w; o2 < NCLS; o2 += 4) {
            const int row = o0 + 5 + o2;
            const float4 wv = *(const float4*)&W[(size_t)row * INCH + l * 4];
            const float4 cv = *(const float4*)&col[l * 4];
            float pr = wv.x*cv.x + wv.y*cv.y + wv.z*cv.z + wv.w*cv.w;
            for (int off = 32; off; off >>= 1) pr += __shfl_down(pr, off);
            if (l == 0) xsh[5 + o2] = pr + bias[row];
        }
        if (tid < 4) {                        // xy/wh raw from existing buf
            const int f = a * 5 + tid;
            const float raw = ((const float*)&buf[0][f][g])[e]
                            + ((const float*)&buf[1][f][g])[e]
                            + ((const float*)&buf[2][f][g])[e]
                            + ((const float*)&buf[3][f][g])[e];
            xsh[tid] = raw + bias[a*NCg + tid];
        }
        if (tid == 4) xsh[4] = 0.f;
        if (tid < 3) sacc[tid] = 0.f;
        __syncthreads();

        if (tid < NCg) {
            const float* ga = gaux + (size_t)t * 8;
            const float sval = ga[4];
            const int gcls = gint[t*2 + 1];
            float val = xsh[tid];
            float term; int slot;
            if (tid < 2) {                       // xy BCE * sval
                float tgt = ga[tid];
                float pp2 = sigm(val);
                term = -(tgt * safe_log(pp2) + (1.f - tgt) * safe_log(1.f - pp2)) * sval;
                slot = 0;
            } else if (tid < 4) {                // wh MSE * 0.5*sval
                float tgt = ga[tid];             // ga[2], ga[3]
                float d = val - tgt;
                term = 0.5f * sval * d * d;
                slot = 1;
            } else if (tid == 4) {               // conf handled in phase 2
                term = 0.f; slot = 2;
            } else {                             // cls BCE
                float tgt = ((tid - 5) == gcls) ? 1.f : 0.f;
                float pp2 = sigm(val);
                term = -(tgt * safe_log(pp2) + (1.f - tgt) * safe_log(1.f - pp2));
                slot = 2;
            }
            atomicAdd(&sacc[slot], term);
        }
        __syncthreads();
        if (tid == 0) {
            atomicAdd(&acc[0], sacc[0]);
            atomicAdd(&acc[1], sacc[1]);
            atomicAdd(&acc[3], sacc[2]);
        }
    }

    // ============ finalize ticket ==========================================
    if (tid == 0) {
        __threadfence();
        const int v = atomicAdd(done, 1);
        if (v == TOTBLK - 1) {
            const float xy = atomicAdd(&acc[0], 0.f);
            const float wh = atomicAdd(&acc[1], 0.f);
            const float ob = atomicAdd(&acc[2], 0.f);
            const float cl = atomicAdd(&acc[3], 0.f);
            out[0] = xy + wh + ob + cl;
            out[1] = xy; out[2] = wh; out[3] = ob; out[4] = cl;
        }
    }
}

extern "C" void kernel_launch(void* const* d_in, const int* in_sizes, int n_in,
                              void* d_out, int out_size, void* d_ws, size_t ws_size,
                              hipStream_t stream)
{
    const float* xin    = (const float*)d_in[0];
    const float* labels = (const float*)d_in[1];
    const float* W      = (const float*)d_in[2];
    const float* bias   = (const float*)d_in[3];

    char* ws = (char*)d_ws;
    float* acc    = (float*)(ws + ACC_OFF);
    int*   hasAny = (int*)  (ws + HAS_OFF);
    int*   done   = (int*)  (ws + DONE_OFF);
    float* Wt     = (float*)(ws + WT_OFF);
    float* gbox   = (float*)(ws + GB_OFF);
    float* gaux   = (float*)(ws + GA_OFF);
    int*   gint   = (int*)  (ws + GI_OFF);
    float* out    = (float*)d_out;

    k_labels<<<16, 256, 0, stream>>>(labels, W, Wt, gbox, gaux, gint, hasAny, acc, done);

    k_mega<<<dim3(GBLK, NB), 256, 0, stream>>>(xin, Wt, W, bias, gbox, gaux,
                                               gint, hasAny, acc, done, out);
}